// Round 1
// baseline (366.761 us; speedup 1.0000x reference)
//
#include <hip/hip_runtime.h>
#include <hip/hip_bf16.h>
#include <math.h>

// DistanceLoss: per-row argmax over C=1000 classes, gather 2D centers for
// predicted & true class, Euclidean distance / 255, summed over B=65536 rows.
// Memory-bound on reading pred (262 MB fp32). One wave per row.

#ifndef DL_B
#define DL_B 65536
#endif
#ifndef DL_C
#define DL_C 1000
#endif

__global__ __launch_bounds__(256) void
DistanceLoss_kernel(const float* __restrict__ pred,
                    const int* __restrict__ true_idx,
                    const float* __restrict__ centers,
                    float* __restrict__ out,
                    int B, int C) {
    const int lane = threadIdx.x & 63;
    const int wave_in_block = threadIdx.x >> 6;
    const int waves_per_block = blockDim.x >> 6;
    const int gwave = blockIdx.x * waves_per_block + wave_in_block;
    const int nwaves = gridDim.x * waves_per_block;
    const int C4 = C >> 2;  // 250 float4 per row (C=1000 divisible by 4)

    float local_sum = 0.0f;

    for (int row = gwave; row < B; row += nwaves) {
        const float4* p = reinterpret_cast<const float4*>(pred + (size_t)row * C);

        float best = -INFINITY;
        int bidx = 0x7fffffff;

        // Lanes stride over the row's float4s: lane i reads p[i], p[i+64], ...
        // -> consecutive 16B per lane = fully coalesced 1 KB/wave/load.
        for (int j = lane; j < C4; j += 64) {
            float4 v = p[j];
            int base = j << 2;
            // strict '>' keeps FIRST occurrence of max within this lane
            // (indices are visited in increasing order).
            if (v.x > best) { best = v.x; bidx = base;     }
            if (v.y > best) { best = v.y; bidx = base + 1; }
            if (v.z > best) { best = v.z; bidx = base + 2; }
            if (v.w > best) { best = v.w; bidx = base + 3; }
        }

        // Wave-wide argmax reduction (64 lanes, 6 butterfly steps).
        // Tie-break: lower index wins (jnp.argmax first-occurrence semantics).
        #pragma unroll
        for (int off = 32; off > 0; off >>= 1) {
            float ov = __shfl_xor(best, off, 64);
            int   oi = __shfl_xor(bidx, off, 64);
            if (ov > best || (ov == best && oi < bidx)) { best = ov; bidx = oi; }
        }

        if (lane == 0) {
            int t = true_idx[row];
            float ax = centers[2 * bidx],     ay = centers[2 * bidx + 1];
            float bx = centers[2 * t],        by = centers[2 * t + 1];
            float dx = ax - bx, dy = ay - by;
            local_sum += sqrtf(dx * dx + dy * dy) * (1.0f / 255.0f);
        }
    }

    // Block reduction: only lane 0 of each wave holds a partial sum.
    __shared__ float ssum[16];
    if (lane == 0) ssum[wave_in_block] = local_sum;
    __syncthreads();
    if (threadIdx.x == 0) {
        float s = 0.0f;
        for (int w = 0; w < waves_per_block; ++w) s += ssum[w];
        atomicAdd(out, s);  // device-scope by default on CDNA
    }
}

extern "C" void kernel_launch(void* const* d_in, const int* in_sizes, int n_in,
                              void* d_out, int out_size, void* d_ws, size_t ws_size,
                              hipStream_t stream) {
    const float* pred     = (const float*)d_in[0];   // [B, C] fp32
    const int*   true_idx = (const int*)d_in[1];     // [B] int32 (harness convention)
    const float* centers  = (const float*)d_in[2];   // [C, 2] fp32
    float* out = (float*)d_out;                      // scalar fp32

    const int B = in_sizes[1];          // 65536
    const int C = in_sizes[0] / B;      // 1000

    // d_out is poisoned to 0xAA before every timed launch -> zero it here.
    hipMemsetAsync(out, 0, sizeof(float), stream);

    // 2048 blocks x 256 threads = 8192 waves -> 8 rows/wave, full occupancy.
    const int block = 256;
    const int grid  = 2048;
    DistanceLoss_kernel<<<grid, block, 0, stream>>>(pred, true_idx, centers, out, B, C);
}

// Round 2
// 356.357 us; speedup vs baseline: 1.0292x; 1.0292x over previous
//
#include <hip/hip_runtime.h>
#include <hip/hip_bf16.h>
#include <math.h>

// DistanceLoss: per-row argmax over C=1000 fp32 classes, gather 2D centers
// for predicted & true class, Euclidean distance / 255, summed over B rows.
// Memory-bound: 262 MB pred read. One wave per row, 2 rows per iteration.
//
// C=1000 -> 250 float4 per row. Each lane loads j, j+64, j+128, min(j+192,249):
// 4 unconditional coalesced 16B loads (the clamp re-reads real elements
// 996..999 with their true indices -- argmax-safe duplicates, no divergence).

__device__ __forceinline__ void row_argmax(const float4* __restrict__ p,
                                           int lane, float& best, int& bidx) {
    const int j0 = lane;
    const int j1 = lane + 64;
    const int j2 = lane + 128;
    int j3 = lane + 192; if (j3 > 249) j3 = 249;

    float4 v0 = p[j0];
    float4 v1 = p[j1];
    float4 v2 = p[j2];
    float4 v3 = p[j3];

    best = v0.x; bidx = (j0 << 2);
    // strict '>' + increasing visit order => first-occurrence semantics per lane
    #define DL_ARGM(v, i) if ((v) > best) { best = (v); bidx = (i); }
    DL_ARGM(v0.y, (j0 << 2) + 1) DL_ARGM(v0.z, (j0 << 2) + 2) DL_ARGM(v0.w, (j0 << 2) + 3)
    DL_ARGM(v1.x, (j1 << 2))     DL_ARGM(v1.y, (j1 << 2) + 1)
    DL_ARGM(v1.z, (j1 << 2) + 2) DL_ARGM(v1.w, (j1 << 2) + 3)
    DL_ARGM(v2.x, (j2 << 2))     DL_ARGM(v2.y, (j2 << 2) + 1)
    DL_ARGM(v2.z, (j2 << 2) + 2) DL_ARGM(v2.w, (j2 << 2) + 3)
    DL_ARGM(v3.x, (j3 << 2))     DL_ARGM(v3.y, (j3 << 2) + 1)
    DL_ARGM(v3.z, (j3 << 2) + 2) DL_ARGM(v3.w, (j3 << 2) + 3)
    #undef DL_ARGM
}

__device__ __forceinline__ void wave_argmax(float& best, int& bidx) {
    // 64-lane butterfly; tie-break toward lower index (jnp.argmax semantics).
    #pragma unroll
    for (int off = 32; off > 0; off >>= 1) {
        float ov = __shfl_xor(best, off, 64);
        int   oi = __shfl_xor(bidx, off, 64);
        if (ov > best || (ov == best && oi < bidx)) { best = ov; bidx = oi; }
    }
}

__global__ __launch_bounds__(256) void
DistanceLoss_kernel(const float* __restrict__ pred,
                    const int* __restrict__ true_idx,
                    const float* __restrict__ centers,
                    float* __restrict__ out,
                    int B) {
    const int lane = threadIdx.x & 63;
    const int wib  = threadIdx.x >> 6;          // 4 waves per 256-thread block
    const int gwave  = blockIdx.x * 4 + wib;
    const int nwaves = gridDim.x * 4;

    float local_sum = 0.0f;

    int row = gwave;
    // 2-row unroll: 8 independent 16B loads in flight per lane.
    for (; row + nwaves < B; row += 2 * nwaves) {
        const int rowB = row + nwaves;
        const float4* pa = reinterpret_cast<const float4*>(pred + (size_t)row  * 1000);
        const float4* pb = reinterpret_cast<const float4*>(pred + (size_t)rowB * 1000);

        float bestA, bestB; int idxA, idxB;
        row_argmax(pa, lane, bestA, idxA);
        row_argmax(pb, lane, bestB, idxB);
        wave_argmax(bestA, idxA);
        wave_argmax(bestB, idxB);

        if (lane == 0) {
            int ta = true_idx[row], tb = true_idx[rowB];
            float ax0 = centers[2 * idxA], ay0 = centers[2 * idxA + 1];
            float bx0 = centers[2 * ta],   by0 = centers[2 * ta + 1];
            float dx0 = ax0 - bx0, dy0 = ay0 - by0;
            float ax1 = centers[2 * idxB], ay1 = centers[2 * idxB + 1];
            float bx1 = centers[2 * tb],   by1 = centers[2 * tb + 1];
            float dx1 = ax1 - bx1, dy1 = ay1 - by1;
            local_sum += sqrtf(dx0 * dx0 + dy0 * dy0) * (1.0f / 255.0f)
                       + sqrtf(dx1 * dx1 + dy1 * dy1) * (1.0f / 255.0f);
        }
    }
    // tail (B=65536, nwaves=8192 -> no tail in practice, kept for safety)
    for (; row < B; row += nwaves) {
        const float4* p = reinterpret_cast<const float4*>(pred + (size_t)row * 1000);
        float best; int bidx;
        row_argmax(p, lane, best, bidx);
        wave_argmax(best, bidx);
        if (lane == 0) {
            int t = true_idx[row];
            float ax = centers[2 * bidx], ay = centers[2 * bidx + 1];
            float bx = centers[2 * t],    by = centers[2 * t + 1];
            float dx = ax - bx, dy = ay - by;
            local_sum += sqrtf(dx * dx + dy * dy) * (1.0f / 255.0f);
        }
    }

    __shared__ float ssum[4];
    if (lane == 0) ssum[wib] = local_sum;
    __syncthreads();
    if (threadIdx.x == 0) {
        float s = ssum[0] + ssum[1] + ssum[2] + ssum[3];
        atomicAdd(out, s);  // device-scope by default on CDNA
    }
}

extern "C" void kernel_launch(void* const* d_in, const int* in_sizes, int n_in,
                              void* d_out, int out_size, void* d_ws, size_t ws_size,
                              hipStream_t stream) {
    const float* pred     = (const float*)d_in[0];   // [B, 1000] fp32
    const int*   true_idx = (const int*)d_in[1];     // [B] int32
    const float* centers  = (const float*)d_in[2];   // [1000, 2] fp32
    float* out = (float*)d_out;

    const int B = in_sizes[1];  // 65536

    // d_out is re-poisoned to 0xAA before every timed launch -> zero it.
    hipMemsetAsync(out, 0, sizeof(float), stream);

    // 2048 blocks x 4 waves = 8192 waves = full device residency; 8 rows/wave.
    DistanceLoss_kernel<<<2048, 256, 0, stream>>>(pred, true_idx, centers, out, B);
}